// Round 12
// baseline (173.335 us; speedup 1.0000x reference)
//
#include <hip/hip_runtime.h>

// AttentionHead: B=4, S=2048, D=1024, fp32 in/out, bf16 MFMA compute.
// G = Wq·Wk^T  =>  S = Xq·G·Xk^T (K-projection eliminated).
// Max-free softmax: P = exp(S/32) fused into scores epilogue + row-sum partials;
// PV scales by 1/rowsum.
// projTV: 256x256 8-phase pipelined core. scores/pv: NF-templated single-buffer
// core (pv = R9-proven NF=2 grid-1024 LPT). cvtX: non-temporal streaming.

typedef __attribute__((ext_vector_type(8))) short short8;
typedef __attribute__((ext_vector_type(4))) float floatx4;

static constexpr long long XE = 8388608LL;  // 4*2048*1024
static constexpr long long WE = 1048576LL;  // 1024*1024

static __device__ __forceinline__ unsigned short f2b(float f) {
  unsigned u = __builtin_bit_cast(unsigned, f);
  u = (u + 0x7fffu + ((u >> 16) & 1u)) >> 16;
  return (unsigned short)u;
}

static __device__ __forceinline__ void gload16(const unsigned short* g, unsigned short* l) {
  __builtin_amdgcn_global_load_lds(
      (const __attribute__((address_space(1))) unsigned int*)g,
      (__attribute__((address_space(3))) unsigned int*)l, 16, 0, 0);
}

#define VMCNT(n) asm volatile("s_waitcnt vmcnt(" #n ")" ::: "memory")
#define LGKM0() asm volatile("s_waitcnt lgkmcnt(0)" ::: "memory")
#define BARRIER() do { asm volatile("" ::: "memory"); __builtin_amdgcn_s_barrier(); asm volatile("" ::: "memory"); } while (0)

// ============ projTV: 256x256, BK=64x2, 8-wave, 8-phase ============
#define STAGE(base, matoff, h, slot, kt) do {                                  \
    const unsigned short* _s = (base) + (h) * 131072 + (kt) * 64;              \
    char* _d = sb + (slot) * 65536 + (matoff) + (h) * 16384 + dwave;           \
    gload16(_s, (unsigned short*)_d);                                          \
    gload16(_s + 65536, (unsigned short*)(_d + 8192));                         \
  } while (0)

#define READ_A(slot, mb) do {                                                  \
    const char* _p = sb + (slot) * 65536 + aoffb + (mb) * 2048;                \
    af[0][0] = *(const short8*)(_p + c0);        af[0][1] = *(const short8*)(_p + c1); \
    af[1][0] = *(const short8*)(_p + 2048 + c0); af[1][1] = *(const short8*)(_p + 2048 + c1); \
    af[2][0] = *(const short8*)(_p + 4096 + c0); af[2][1] = *(const short8*)(_p + 4096 + c1); \
    af[3][0] = *(const short8*)(_p + 6144 + c0); af[3][1] = *(const short8*)(_p + 6144 + c1); \
  } while (0)

#define READ_B(slot, nb, bfx) do {                                             \
    const char* _p = sb + (slot) * 65536 + boffb + (nb) * 2048;                \
    bfx[0][0] = *(const short8*)(_p + c0);        bfx[0][1] = *(const short8*)(_p + c1); \
    bfx[1][0] = *(const short8*)(_p + 2048 + c0); bfx[1][1] = *(const short8*)(_p + 2048 + c1); \
  } while (0)

#define MF16(MB, NB, bfx) do {                                                 \
    __builtin_amdgcn_s_setprio(1);                                             \
    _Pragma("unroll")                                                          \
    for (int _m = 0; _m < 4; ++_m) {                                           \
      _Pragma("unroll")                                                        \
      for (int _n = 0; _n < 2; ++_n) {                                         \
        acc[(MB) + _m][(NB) + _n] = __builtin_amdgcn_mfma_f32_16x16x32_bf16(   \
            af[_m][0], bfx[_n][0], acc[(MB) + _m][(NB) + _n], 0, 0, 0);        \
        acc[(MB) + _m][(NB) + _n] = __builtin_amdgcn_mfma_f32_16x16x32_bf16(   \
            af[_m][1], bfx[_n][1], acc[(MB) + _m][(NB) + _n], 0, 0, 0);        \
      } }                                                                      \
    __builtin_amdgcn_s_setprio(0);                                             \
  } while (0)

__global__ __launch_bounds__(512, 2) void projTV8(
    const unsigned short* __restrict__ Xb, const unsigned short* __restrict__ WvT,
    const unsigned short* __restrict__ Gt, unsigned short* __restrict__ Tb,
    unsigned short* __restrict__ Vt) {
  extern __shared__ char sb[];
  const int orig = blockIdx.x;
  const int w = (orig & 7) * 32 + (orig >> 3);  // 256 = 8*32
  const unsigned short *Aop, *Bop;
  unsigned short* C;
  int ldc, bi, bj;
  if (w < 128) { Aop = Xb + XE; Bop = Gt; C = Tb; ldc = 1024; bi = w >> 2; bj = w & 3; }
  else { const int j = w - 128; Aop = WvT; Bop = Xb; C = Vt; ldc = 8192; bi = j & 3; bj = j >> 2; }

  const int tid = threadIdx.x, wave = tid >> 6, lane = tid & 63;
  const int wm = wave >> 2, wn = wave & 3, frow = lane & 15, hi = lane >> 4;
  const int r0 = tid >> 3, p0 = ((tid & 7) ^ (r0 & 7)) * 8;
  const int dwave = wave * 1024;
  const int sx = frow & 7;
  const int c0 = (hi ^ sx) * 16, c1 = ((4 + hi) ^ sx) * 16;
  const int aoffb = (wm * 128 + frow) * 128;
  const int boffb = 32768 + (wn * 64 + frow) * 128;
  const unsigned short* Ab = Aop + (long long)(bi * 256 + r0) * 1024 + p0;
  const unsigned short* Bb = Bop + (long long)(bj * 256 + r0) * 1024 + p0;

  short8 af[4][2], bf0[2][2], bf1[2][2];
  floatx4 acc[8][4] = {};

  STAGE(Ab, 0, 0, 0, 0);     STAGE(Ab, 0, 1, 0, 0);
  STAGE(Bb, 32768, 0, 0, 0); STAGE(Bb, 32768, 1, 0, 0);
  STAGE(Bb, 32768, 0, 1, 1); STAGE(Bb, 32768, 1, 1, 1);
  VMCNT(4);
  BARRIER();

  for (int t = 0; t < 8; ++t) {
    const int kt1 = 2 * t + 1, kt2 = 2 * t + 2, kt3 = 2 * t + 3;
    const bool pf = t < 7;
    READ_A(0, 0); READ_B(0, 0, bf0);
    STAGE(Ab, 0, 0, 1, kt1);
    BARRIER(); LGKM0();
    MF16(0, 0, bf0);
    BARRIER();
    READ_B(0, 2, bf1);
    STAGE(Ab, 0, 1, 1, kt1);
    BARRIER(); LGKM0();
    MF16(0, 2, bf1);
    BARRIER();
    READ_A(0, 4);
    if (pf) STAGE(Bb, 32768, 0, 0, kt2);
    BARRIER(); LGKM0();
    MF16(4, 2, bf1);
    BARRIER();
    if (pf) STAGE(Bb, 32768, 1, 0, kt2);
    BARRIER();
    MF16(4, 0, bf0);
    if (pf) { VMCNT(4); } else { VMCNT(0); }
    BARRIER();
    READ_A(1, 0); READ_B(1, 0, bf0);
    if (pf) STAGE(Ab, 0, 0, 0, kt2);
    BARRIER(); LGKM0();
    MF16(0, 0, bf0);
    BARRIER();
    READ_B(1, 2, bf1);
    if (pf) STAGE(Ab, 0, 1, 0, kt2);
    BARRIER(); LGKM0();
    MF16(0, 2, bf1);
    BARRIER();
    READ_A(1, 4);
    if (pf) STAGE(Bb, 32768, 0, 1, kt3);
    BARRIER(); LGKM0();
    MF16(4, 2, bf1);
    BARRIER();
    if (pf) STAGE(Bb, 32768, 1, 1, kt3);
    BARRIER();
    MF16(4, 0, bf0);
    if (pf) { VMCNT(4); } else { VMCNT(0); }
    BARRIER();
  }

  const long long crow0 = (long long)bi * 256 + wm * 128 + hi * 4;
  const int ccol = bj * 256 + wn * 64 + frow;
#pragma unroll
  for (int m = 0; m < 8; ++m)
#pragma unroll
    for (int j = 0; j < 4; ++j) {
      unsigned short* cp = C + (crow0 + m * 16 + j) * (long long)ldc + ccol;
#pragma unroll
      for (int n = 0; n < 4; ++n) cp[n * 16] = f2b(acc[m][n][j]);
    }
}

// ============ single-buffer BK=64 core (gt / scores / pv) ============
template <int NF>
static __device__ __forceinline__ void gemm_loop(
    const unsigned short* __restrict__ A, const unsigned short* __restrict__ Bt,
    int lda, int ldb, int nk, int bi, int bj,
    unsigned short* lA, unsigned short* lB, floatx4 acc[4][NF]) {
  const int t = threadIdx.x, wave = t >> 6, lane = t & 63;
  const int wr = wave >> 1, wc = wave & 1;
  const int sr = lane >> 3;
  const int sc = ((lane & 7) ^ sr) * 8;
  const unsigned short* gA = A + (long long)(bi * 128 + wave * 32 + sr) * lda + sc;
  const unsigned short* gB = Bt + (long long)(bj * (NF * 32) + wave * (NF * 8) + sr) * ldb + sc;
  unsigned short* lAw = lA + wave * 2048;
  unsigned short* lBw = lB + wave * (NF * 512);
  const int frow = lane & 15, hi = lane >> 4;

  for (int ks = 0; ks < nk; ++ks) {
    const long long k0 = (long long)ks * 64;
    __syncthreads();
#pragma unroll
    for (int g = 0; g < 4; ++g)
      gload16(gA + (long long)g * 8 * lda + k0, lAw + g * 512);
#pragma unroll
    for (int g = 0; g < NF; ++g)
      gload16(gB + (long long)g * 8 * ldb + k0, lBw + g * 512);
    __syncthreads();
#pragma unroll
    for (int kk = 0; kk < 2; ++kk) {
      const int ch = (kk * 4 + hi) ^ (frow & 7);
      short8 af[4], bf[NF];
#pragma unroll
      for (int m = 0; m < 4; ++m)
        af[m] = *(const short8*)&lA[(wr * 64 + m * 16 + frow) * 64 + ch * 8];
#pragma unroll
      for (int n = 0; n < NF; ++n)
        bf[n] = *(const short8*)&lB[(wc * (NF * 16) + n * 16 + frow) * 64 + ch * 8];
#pragma unroll
      for (int m = 0; m < 4; ++m)
#pragma unroll
        for (int n = 0; n < NF; ++n)
          acc[m][n] = __builtin_amdgcn_mfma_f32_16x16x32_bf16(af[m], bf[n], acc[m][n], 0, 0, 0);
    }
  }
}

// Gt[j][i] = sum_d Wk[j][d]*Wq[i][d], grid (8,8)
__global__ __launch_bounds__(256) void gt_kernel(
    const unsigned short* __restrict__ WkB, const unsigned short* __restrict__ WqB,
    unsigned short* __restrict__ Gt) {
  __shared__ __align__(16) unsigned short lA[8192], lB[8192];
  floatx4 acc[4][4] = {};
  gemm_loop<4>(WkB, WqB, 1024, 1024, 16, blockIdx.x, blockIdx.y, lA, lB, acc);
  const int tid = threadIdx.x, wave = tid >> 6, lane = tid & 63;
  const int wr = wave >> 1, wc = wave & 1, frow = lane & 15, hi = lane >> 4;
  const long long crow0 = (long long)blockIdx.x * 128 + wr * 64 + hi * 4;
  const int ccol = blockIdx.y * 128 + wc * 64 + frow;
#pragma unroll
  for (int m = 0; m < 4; ++m)
#pragma unroll
    for (int j = 0; j < 4; ++j) {
      unsigned short* cp = Gt + (crow0 + m * 16 + j) * 1024 + ccol;
#pragma unroll
      for (int n = 0; n < 4; ++n) cp[n * 16] = f2b(acc[m][n][j]);
    }
}

// 1-D grid 1088 (=8*136, XCD-swizzled). 128x64 tiles; S = T·Xk^T ;
// P = exp(S/32) bf16 (causal) ; row-sum partials -> Rpart[b][bj64][2048].
__global__ __launch_bounds__(256) void scores_exp(
    const unsigned short* __restrict__ Tb, const unsigned short* __restrict__ Xk,
    unsigned short* __restrict__ P, float* __restrict__ Rpart) {
  __shared__ __align__(16) unsigned short lA[8192], lB[4096];
  const int orig = blockIdx.x;
  const int w = (orig & 7) * 136 + (orig >> 3);
  const int b = w / 272;
  int t2 = w - b * 272;
  int bi = 0;
  while (t2 >= 2 * bi + 2) { t2 -= 2 * bi + 2; ++bi; }
  const int bj = t2;

  floatx4 acc[4][2] = {};
  gemm_loop<2>(Tb + (long long)b * 2048 * 1024, Xk + (long long)b * 2048 * 1024,
               1024, 1024, 16, bi, bj, lA, lB, acc);

  const int tid = threadIdx.x, wave = tid >> 6, lane = tid & 63;
  const int wr = wave >> 1, wc = wave & 1, frow = lane & 15, hi = lane >> 4;
  const bool diag = (bj >= 2 * bi);
  float rp[4][4];
#pragma unroll
  for (int m = 0; m < 4; ++m)
#pragma unroll
    for (int j = 0; j < 4; ++j) {
      const int rloc = wr * 64 + hi * 4 + m * 16 + j;
      const int rglob = bi * 128 + rloc;
      float s = 0.f;
#pragma unroll
      for (int n = 0; n < 2; ++n) {
        const int cglob = bj * 64 + wc * 32 + n * 16 + frow;
        float e = __expf(acc[m][n][j] * 0.03125f);
        if (diag && cglob > rglob) e = 0.f;
        acc[m][n][j] = e;
        s += e;
      }
      rp[m][j] = s;
    }
#pragma unroll
  for (int m = 0; m < 4; ++m)
#pragma unroll
    for (int j = 0; j < 4; ++j) {
      rp[m][j] += __shfl_xor(rp[m][j], 1);
      rp[m][j] += __shfl_xor(rp[m][j], 2);
      rp[m][j] += __shfl_xor(rp[m][j], 4);
      rp[m][j] += __shfl_xor(rp[m][j], 8);
    }
  unsigned short* C = P + (long long)b * 2048 * 2048;
  const long long crow0 = (long long)bi * 128 + wr * 64 + hi * 4;
  const int ccol = bj * 64 + wc * 32 + frow;
#pragma unroll
  for (int m = 0; m < 4; ++m)
#pragma unroll
    for (int j = 0; j < 4; ++j) {
      unsigned short* cp = C + (crow0 + m * 16 + j) * 2048LL + ccol;
      cp[0] = f2b(acc[m][0][j]);
      cp[16] = f2b(acc[m][1][j]);
    }
  __syncthreads();
  float* red = (float*)lA;
  if (frow == 0) {
#pragma unroll
    for (int m = 0; m < 4; ++m)
#pragma unroll
      for (int j = 0; j < 4; ++j)
        red[(wr * 64 + hi * 4 + m * 16 + j) * 2 + wc] = rp[m][j];
  }
  __syncthreads();
  if (tid < 128)
    Rpart[((long long)b * 32 + bj) * 2048 + bi * 128 + tid] = red[tid * 2] + red[tid * 2 + 1];
}

// Rinv[b][row] = 1 / sum_{bj64 <= row>>6} Rpart[b][bj64][row]
__global__ __launch_bounds__(256) void rowsum(
    const float* __restrict__ Rpart, float* __restrict__ Rinv) {
  const int t = blockIdx.x * 256 + threadIdx.x;  // 0..8191
  const int b = t >> 11, row = t & 2047;
  const int nb = (row >> 6) + 1;
  float s = 0.f;
  for (int bj = 0; bj < nb; ++bj) s += Rpart[(b * 32 + bj) * 2048 + row];
  Rinv[t] = 1.f / s;
}

// O = (P V) * Rinv ; grid 1024 (R9-proven). Per-XCD balanced LPT: XCD c gets
// 8 blocks of EVERY bi, heavy-first; per (c,bi) 8 blocks share one (b,P-panel).
__global__ __launch_bounds__(256) void pv_kernel(
    const unsigned short* __restrict__ P, const unsigned short* __restrict__ Vt,
    const float* __restrict__ Rinv, float* __restrict__ out) {
  __shared__ __align__(16) unsigned short lA[8192], lB[4096];
  const int orig = blockIdx.x;
  const int c = orig & 7, i = orig >> 3;  // XCD, order within XCD (0..127)
  const int bi = 15 - (i >> 3);           // heavy-first
  const int rr = (i & 7) + c * 8;         // 0..63
  const int b = rr >> 4, bj = rr & 15;
  floatx4 acc[4][2] = {};
  gemm_loop<2>(P + (long long)b * 2048 * 2048, Vt + (long long)b * 2048, 2048, 8192,
               (bi + 1) * 2, bi, bj, lA, lB, acc);
  const int tid = threadIdx.x, wave = tid >> 6, lane = tid & 63;
  const int wr = wave >> 1, wc = wave & 1, frow = lane & 15, hi = lane >> 4;
  float* C = out + (long long)b * 2048 * 1024;
  const float* Ri = Rinv + b * 2048;
#pragma unroll
  for (int m = 0; m < 4; ++m)
#pragma unroll
    for (int j = 0; j < 4; ++j) {
      const int row = bi * 128 + wr * 64 + hi * 4 + m * 16 + j;
      const float riv = Ri[row];
      float* cp = C + (long long)row * 1024 + bj * 64 + wc * 32 + frow;
      cp[0] = acc[m][0][j] * riv;
      cp[16] = acc[m][1][j] * riv;
    }
}

// X fp32->bf16, non-temporal both sides (read-once stream; bf16 consumed much
// later from L3/HBM). Grid 3072 = 1024 blocks per tensor.
__global__ __launch_bounds__(256) void cvtX(
    const float* __restrict__ Xk, const float* __restrict__ Xv,
    const float* __restrict__ Xq, unsigned short* __restrict__ Xb) {
  const int bx = blockIdx.x, t = threadIdx.x;
  const int y = bx >> 10, sub = bx & 1023;
  const float* in = y == 0 ? Xv : (y == 1 ? Xq : Xk);
  unsigned short* o = Xb + (long long)y * XE;
  const int n8 = (int)(XE / 8), stride = 1024 * 256;
  for (int i = sub * 256 + t; i < n8; i += stride) {
    const floatx4* src = (const floatx4*)in + 2 * (long long)i;
    floatx4 a = __builtin_nontemporal_load(src);
    floatx4 d = __builtin_nontemporal_load(src + 1);
    short8 v;
    v[0] = (short)f2b(a[0]); v[1] = (short)f2b(a[1]);
    v[2] = (short)f2b(a[2]); v[3] = (short)f2b(a[3]);
    v[4] = (short)f2b(d[0]); v[5] = (short)f2b(d[1]);
    v[6] = (short)f2b(d[2]); v[7] = (short)f2b(d[3]);
    __builtin_nontemporal_store(v, (short8*)o + i);
  }
}

// W converts (cached; gt consumes immediately): grid 384 =
// [0,128): Wq,Wk plain ; [128,384): Wv transpose.
__global__ __launch_bounds__(256) void cvtW(
    const float* __restrict__ Wq, const float* __restrict__ Wk,
    const float* __restrict__ Wv, unsigned short* __restrict__ WqB,
    unsigned short* __restrict__ WkB, unsigned short* __restrict__ WvT) {
  __shared__ unsigned short tile[64][65];
  const int bx = blockIdx.x, t = threadIdx.x;
  if (bx < 128) {
    const int y = bx >> 6, sub = bx & 63;
    const float* in = y == 0 ? Wq : Wk;
    unsigned short* o = y == 0 ? WqB : WkB;
    const int n8 = (int)(WE / 8), stride = 64 * 256;
    for (int i = sub * 256 + t; i < n8; i += stride) {
      const float4* src = (const float4*)in + 2 * (long long)i;
      float4 a = src[0], d = src[1];
      short8 v;
      v[0] = (short)f2b(a.x); v[1] = (short)f2b(a.y);
      v[2] = (short)f2b(a.z); v[3] = (short)f2b(a.w);
      v[4] = (short)f2b(d.x); v[5] = (short)f2b(d.y);
      v[6] = (short)f2b(d.z); v[7] = (short)f2b(d.w);
      ((short8*)o)[i] = v;
    }
  } else {
    const int v = bx - 128;
    const int i0 = (v & 15) * 64, j0 = (v >> 4) * 64;
#pragma unroll
    for (int r = 0; r < 16; ++r) {
      int lin = r * 256 + t;
      int i = lin >> 6, j = lin & 63;
      tile[i][j] = f2b(Wv[(long long)(i0 + i) * 1024 + j0 + j]);
    }
    __syncthreads();
#pragma unroll
    for (int r = 0; r < 16; ++r) {
      int lin = r * 256 + t;
      int o = lin >> 6, i = lin & 63;
      WvT[(long long)(j0 + o) * 1024 + i0 + i] = tile[i][o];
    }
  }
}

extern "C" void kernel_launch(void* const* d_in, const int* in_sizes, int n_in,
                              void* d_out, int out_size, void* d_ws, size_t ws_size,
                              hipStream_t stream) {
  const float* Xk = (const float*)d_in[0];
  const float* Xv = (const float*)d_in[1];
  const float* Xq = (const float*)d_in[2];
  const float* Wk = (const float*)d_in[3];
  const float* Wv = (const float*)d_in[4];
  const float* Wq = (const float*)d_in[5];
  float* out = (float*)d_out;

  // ws (ushort elems): Xb[3XE: Xv|Xq|Xk] WqB[WE] WkB[WE] WvT[WE] Gt[WE]
  //                    Tb[XE] Vt[XE] Rpart[4*32*2048 f32] Rinv[8192 f32]
  // Pbuf (bf16 P, 2XE) aliases Xv|Xq ONLY (both dead after projTV8).
  unsigned short* ws = (unsigned short*)d_ws;
  unsigned short* Xb = ws;
  unsigned short* WqB = ws + 3 * XE;
  unsigned short* WkB = WqB + WE;
  unsigned short* WvT = WkB + WE;
  unsigned short* Gt = WvT + WE;
  unsigned short* Tb = Gt + WE;
  unsigned short* Vt = Tb + XE;
  float* Rpart = (float*)(Vt + XE);
  float* Rinv = Rpart + 4 * 32 * 2048;
  unsigned short* Pbuf = ws;  // alias over Xv|Xq

  cvtW<<<384, 256, 0, stream>>>(Wq, Wk, Wv, WqB, WkB, WvT);
  gt_kernel<<<dim3(8, 8), 256, 0, stream>>>(WkB, WqB, Gt);
  cvtX<<<3072, 256, 0, stream>>>(Xk, Xv, Xq, Xb);
  projTV8<<<256, 512, 131072, stream>>>(Xb, WvT, Gt, Tb, Vt);
  scores_exp<<<1088, 256, 0, stream>>>(Tb, Xb + 2 * XE, Pbuf, Rpart);
  rowsum<<<32, 256, 0, stream>>>(Rpart, Rinv);
  pv_kernel<<<1024, 256, 0, stream>>>(Pbuf, Vt, Rinv, out);
}

// Round 13
// 172.178 us; speedup vs baseline: 1.0067x; 1.0067x over previous
//
#include <hip/hip_runtime.h>

// AttentionHead: B=4, S=2048, D=1024, fp32 in/out, bf16 MFMA compute.
// G = Wq·Wk^T  =>  S = Xq·G·Xk^T (K-projection eliminated).
// Max-free softmax: P = exp(S/32) fused into scores epilogue + row-sum partials;
// PV scales by 1/rowsum.
// projTV: 256x256 8-phase pipelined core. scores/pv/gt: BK=32 single-buffer
// core (R2-proven granularity: 12KB/step staging, fine-grained overlap).

typedef __attribute__((ext_vector_type(8))) short short8;
typedef __attribute__((ext_vector_type(4))) float floatx4;

static constexpr long long XE = 8388608LL;  // 4*2048*1024
static constexpr long long WE = 1048576LL;  // 1024*1024

static __device__ __forceinline__ unsigned short f2b(float f) {
  unsigned u = __builtin_bit_cast(unsigned, f);
  u = (u + 0x7fffu + ((u >> 16) & 1u)) >> 16;
  return (unsigned short)u;
}

static __device__ __forceinline__ void gload16(const unsigned short* g, unsigned short* l) {
  __builtin_amdgcn_global_load_lds(
      (const __attribute__((address_space(1))) unsigned int*)g,
      (__attribute__((address_space(3))) unsigned int*)l, 16, 0, 0);
}

#define VMCNT(n) asm volatile("s_waitcnt vmcnt(" #n ")" ::: "memory")
#define LGKM0() asm volatile("s_waitcnt lgkmcnt(0)" ::: "memory")
#define BARRIER() do { asm volatile("" ::: "memory"); __builtin_amdgcn_s_barrier(); asm volatile("" ::: "memory"); } while (0)

// ============ projTV: 256x256, BK=64x2, 8-wave, 8-phase ============
#define STAGE(base, matoff, h, slot, kt) do {                                  \
    const unsigned short* _s = (base) + (h) * 131072 + (kt) * 64;              \
    char* _d = sb + (slot) * 65536 + (matoff) + (h) * 16384 + dwave;           \
    gload16(_s, (unsigned short*)_d);                                          \
    gload16(_s + 65536, (unsigned short*)(_d + 8192));                         \
  } while (0)

#define READ_A(slot, mb) do {                                                  \
    const char* _p = sb + (slot) * 65536 + aoffb + (mb) * 2048;                \
    af[0][0] = *(const short8*)(_p + c0);        af[0][1] = *(const short8*)(_p + c1); \
    af[1][0] = *(const short8*)(_p + 2048 + c0); af[1][1] = *(const short8*)(_p + 2048 + c1); \
    af[2][0] = *(const short8*)(_p + 4096 + c0); af[2][1] = *(const short8*)(_p + 4096 + c1); \
    af[3][0] = *(const short8*)(_p + 6144 + c0); af[3][1] = *(const short8*)(_p + 6144 + c1); \
  } while (0)

#define READ_B(slot, nb, bfx) do {                                             \
    const char* _p = sb + (slot) * 65536 + boffb + (nb) * 2048;                \
    bfx[0][0] = *(const short8*)(_p + c0);        bfx[0][1] = *(const short8*)(_p + c1); \
    bfx[1][0] = *(const short8*)(_p + 2048 + c0); bfx[1][1] = *(const short8*)(_p + 2048 + c1); \
  } while (0)

#define MF16(MB, NB, bfx) do {                                                 \
    __builtin_amdgcn_s_setprio(1);                                             \
    _Pragma("unroll")                                                          \
    for (int _m = 0; _m < 4; ++_m) {                                           \
      _Pragma("unroll")                                                        \
      for (int _n = 0; _n < 2; ++_n) {                                         \
        acc[(MB) + _m][(NB) + _n] = __builtin_amdgcn_mfma_f32_16x16x32_bf16(   \
            af[_m][0], bfx[_n][0], acc[(MB) + _m][(NB) + _n], 0, 0, 0);        \
        acc[(MB) + _m][(NB) + _n] = __builtin_amdgcn_mfma_f32_16x16x32_bf16(   \
            af[_m][1], bfx[_n][1], acc[(MB) + _m][(NB) + _n], 0, 0, 0);        \
      } }                                                                      \
    __builtin_amdgcn_s_setprio(0);                                             \
  } while (0)

__global__ __launch_bounds__(512, 2) void projTV8(
    const unsigned short* __restrict__ Xb, const unsigned short* __restrict__ WvT,
    const unsigned short* __restrict__ Gt, unsigned short* __restrict__ Tb,
    unsigned short* __restrict__ Vt) {
  extern __shared__ char sb[];
  const int orig = blockIdx.x;
  const int w = (orig & 7) * 32 + (orig >> 3);  // 256 = 8*32
  const unsigned short *Aop, *Bop;
  unsigned short* C;
  int ldc, bi, bj;
  if (w < 128) { Aop = Xb + XE; Bop = Gt; C = Tb; ldc = 1024; bi = w >> 2; bj = w & 3; }
  else { const int j = w - 128; Aop = WvT; Bop = Xb; C = Vt; ldc = 8192; bi = j & 3; bj = j >> 2; }

  const int tid = threadIdx.x, wave = tid >> 6, lane = tid & 63;
  const int wm = wave >> 2, wn = wave & 3, frow = lane & 15, hi = lane >> 4;
  const int r0 = tid >> 3, p0 = ((tid & 7) ^ (r0 & 7)) * 8;
  const int dwave = wave * 1024;
  const int sx = frow & 7;
  const int c0 = (hi ^ sx) * 16, c1 = ((4 + hi) ^ sx) * 16;
  const int aoffb = (wm * 128 + frow) * 128;
  const int boffb = 32768 + (wn * 64 + frow) * 128;
  const unsigned short* Ab = Aop + (long long)(bi * 256 + r0) * 1024 + p0;
  const unsigned short* Bb = Bop + (long long)(bj * 256 + r0) * 1024 + p0;

  short8 af[4][2], bf0[2][2], bf1[2][2];
  floatx4 acc[8][4] = {};

  STAGE(Ab, 0, 0, 0, 0);     STAGE(Ab, 0, 1, 0, 0);
  STAGE(Bb, 32768, 0, 0, 0); STAGE(Bb, 32768, 1, 0, 0);
  STAGE(Bb, 32768, 0, 1, 1); STAGE(Bb, 32768, 1, 1, 1);
  VMCNT(4);
  BARRIER();

  for (int t = 0; t < 8; ++t) {
    const int kt1 = 2 * t + 1, kt2 = 2 * t + 2, kt3 = 2 * t + 3;
    const bool pf = t < 7;
    READ_A(0, 0); READ_B(0, 0, bf0);
    STAGE(Ab, 0, 0, 1, kt1);
    BARRIER(); LGKM0();
    MF16(0, 0, bf0);
    BARRIER();
    READ_B(0, 2, bf1);
    STAGE(Ab, 0, 1, 1, kt1);
    BARRIER(); LGKM0();
    MF16(0, 2, bf1);
    BARRIER();
    READ_A(0, 4);
    if (pf) STAGE(Bb, 32768, 0, 0, kt2);
    BARRIER(); LGKM0();
    MF16(4, 2, bf1);
    BARRIER();
    if (pf) STAGE(Bb, 32768, 1, 0, kt2);
    BARRIER();
    MF16(4, 0, bf0);
    if (pf) { VMCNT(4); } else { VMCNT(0); }
    BARRIER();
    READ_A(1, 0); READ_B(1, 0, bf0);
    if (pf) STAGE(Ab, 0, 0, 0, kt2);
    BARRIER(); LGKM0();
    MF16(0, 0, bf0);
    BARRIER();
    READ_B(1, 2, bf1);
    if (pf) STAGE(Ab, 0, 1, 0, kt2);
    BARRIER(); LGKM0();
    MF16(0, 2, bf1);
    BARRIER();
    READ_A(1, 4);
    if (pf) STAGE(Bb, 32768, 0, 1, kt3);
    BARRIER(); LGKM0();
    MF16(4, 2, bf1);
    BARRIER();
    if (pf) STAGE(Bb, 32768, 1, 1, kt3);
    BARRIER();
    MF16(4, 0, bf0);
    if (pf) { VMCNT(4); } else { VMCNT(0); }
    BARRIER();
  }

  const long long crow0 = (long long)bi * 256 + wm * 128 + hi * 4;
  const int ccol = bj * 256 + wn * 64 + frow;
#pragma unroll
  for (int m = 0; m < 8; ++m)
#pragma unroll
    for (int j = 0; j < 4; ++j) {
      unsigned short* cp = C + (crow0 + m * 16 + j) * (long long)ldc + ccol;
#pragma unroll
      for (int n = 0; n < 4; ++n) cp[n * 16] = f2b(acc[m][n][j]);
    }
}

// ============ BK=32 single-buffer core (gt / scores / pv) ============
// Tile 128 x (NF*32); row = 32 elems = 4 chunks of 16B. LDS chunk c of row r
// holds global chunk c^((r>>1)&3) (pre-swizzled source; linear gload dest;
// swizzled read -> 2-way banks max). 3 (NF=2) or 4 (NF=4) wave-loads/step.
template <int NF>
static __device__ __forceinline__ void gemm_loop32(
    const unsigned short* __restrict__ A, const unsigned short* __restrict__ Bt,
    int lda, int ldb, int nk, int bi, int bj,
    unsigned short* lA, unsigned short* lB, floatx4 acc[4][NF]) {
  const int t = threadIdx.x, wave = t >> 6, lane = t & 63;
  const int wr = wave >> 1, wc = wave & 1;
  const int frow = lane & 15, hi = lane >> 4;
  const int rA0 = t >> 2;                          // rows 0..63 (chunk ci = t)
  const int cg = ((t & 3) ^ ((t >> 3) & 3)) * 8;   // source chunk (elements)
  const unsigned short* gA0 = A + (long long)(bi * 128 + rA0) * lda + cg;
  const unsigned short* gB0 = Bt + (long long)(bj * (NF * 32) + rA0) * ldb + cg;
  unsigned short* lAw = lA + wave * 512;
  unsigned short* lBw = lB + wave * 512;
  const int rch = (hi ^ ((frow >> 1) & 3)) * 8;

  for (int ks = 0; ks < nk; ++ks) {
    const long long k0 = (long long)ks * 32;
    __syncthreads();
    gload16(gA0 + k0, lAw);
    gload16(gA0 + (long long)64 * lda + k0, lAw + 2048);
    gload16(gB0 + k0, lBw);
    if constexpr (NF == 4) gload16(gB0 + (long long)64 * ldb + k0, lBw + 2048);
    __syncthreads();
    short8 af[4], bf[NF];
#pragma unroll
    for (int m = 0; m < 4; ++m)
      af[m] = *(const short8*)&lA[(wr * 64 + m * 16 + frow) * 32 + rch];
#pragma unroll
    for (int n = 0; n < NF; ++n)
      bf[n] = *(const short8*)&lB[(wc * (NF * 16) + n * 16 + frow) * 32 + rch];
#pragma unroll
    for (int m = 0; m < 4; ++m)
#pragma unroll
      for (int n = 0; n < NF; ++n)
        acc[m][n] = __builtin_amdgcn_mfma_f32_16x16x32_bf16(af[m], bf[n], acc[m][n], 0, 0, 0);
  }
}

// Gt[j][i] = sum_d Wk[j][d]*Wq[i][d], grid (8,8)
__global__ __launch_bounds__(256) void gt_kernel(
    const unsigned short* __restrict__ WkB, const unsigned short* __restrict__ WqB,
    unsigned short* __restrict__ Gt) {
  __shared__ __align__(16) unsigned short lA[4096], lB[4096];
  floatx4 acc[4][4] = {};
  gemm_loop32<4>(WkB, WqB, 1024, 1024, 32, blockIdx.x, blockIdx.y, lA, lB, acc);
  const int tid = threadIdx.x, wave = tid >> 6, lane = tid & 63;
  const int wr = wave >> 1, wc = wave & 1, frow = lane & 15, hi = lane >> 4;
  const long long crow0 = (long long)blockIdx.x * 128 + wr * 64 + hi * 4;
  const int ccol = blockIdx.y * 128 + wc * 64 + frow;
#pragma unroll
  for (int m = 0; m < 4; ++m)
#pragma unroll
    for (int j = 0; j < 4; ++j) {
      unsigned short* cp = Gt + (crow0 + m * 16 + j) * 1024 + ccol;
#pragma unroll
      for (int n = 0; n < 4; ++n) cp[n * 16] = f2b(acc[m][n][j]);
    }
}

// 1-D grid 1088 (=8*136, XCD-swizzled). 128x64 tiles; S = T·Xk^T ;
// P = exp(S/32) bf16 (causal) ; row-sum partials -> Rpart[b][bj64][2048].
__global__ __launch_bounds__(256) void scores_exp(
    const unsigned short* __restrict__ Tb, const unsigned short* __restrict__ Xk,
    unsigned short* __restrict__ P, float* __restrict__ Rpart) {
  __shared__ __align__(16) unsigned short lA[4096], lB[2048];
  const int orig = blockIdx.x;
  const int w = (orig & 7) * 136 + (orig >> 3);
  const int b = w / 272;
  int t2 = w - b * 272;
  int bi = 0;
  while (t2 >= 2 * bi + 2) { t2 -= 2 * bi + 2; ++bi; }
  const int bj = t2;

  floatx4 acc[4][2] = {};
  gemm_loop32<2>(Tb + (long long)b * 2048 * 1024, Xk + (long long)b * 2048 * 1024,
                 1024, 1024, 32, bi, bj, lA, lB, acc);

  const int tid = threadIdx.x, wave = tid >> 6, lane = tid & 63;
  const int wr = wave >> 1, wc = wave & 1, frow = lane & 15, hi = lane >> 4;
  const bool diag = (bj >= 2 * bi);
  float rp[4][4];
#pragma unroll
  for (int m = 0; m < 4; ++m)
#pragma unroll
    for (int j = 0; j < 4; ++j) {
      const int rloc = wr * 64 + hi * 4 + m * 16 + j;
      const int rglob = bi * 128 + rloc;
      float s = 0.f;
#pragma unroll
      for (int n = 0; n < 2; ++n) {
        const int cglob = bj * 64 + wc * 32 + n * 16 + frow;
        float e = __expf(acc[m][n][j] * 0.03125f);
        if (diag && cglob > rglob) e = 0.f;
        acc[m][n][j] = e;
        s += e;
      }
      rp[m][j] = s;
    }
#pragma unroll
  for (int m = 0; m < 4; ++m)
#pragma unroll
    for (int j = 0; j < 4; ++j) {
      rp[m][j] += __shfl_xor(rp[m][j], 1);
      rp[m][j] += __shfl_xor(rp[m][j], 2);
      rp[m][j] += __shfl_xor(rp[m][j], 4);
      rp[m][j] += __shfl_xor(rp[m][j], 8);
    }
  unsigned short* C = P + (long long)b * 2048 * 2048;
  const long long crow0 = (long long)bi * 128 + wr * 64 + hi * 4;
  const int ccol = bj * 64 + wc * 32 + frow;
#pragma unroll
  for (int m = 0; m < 4; ++m)
#pragma unroll
    for (int j = 0; j < 4; ++j) {
      unsigned short* cp = C + (crow0 + m * 16 + j) * 2048LL + ccol;
      cp[0] = f2b(acc[m][0][j]);
      cp[16] = f2b(acc[m][1][j]);
    }
  __syncthreads();
  float* red = (float*)lA;
  if (frow == 0) {
#pragma unroll
    for (int m = 0; m < 4; ++m)
#pragma unroll
      for (int j = 0; j < 4; ++j)
        red[(wr * 64 + hi * 4 + m * 16 + j) * 2 + wc] = rp[m][j];
  }
  __syncthreads();
  if (tid < 128)
    Rpart[((long long)b * 32 + bj) * 2048 + bi * 128 + tid] = red[tid * 2] + red[tid * 2 + 1];
}

// Rinv[b][row] = 1 / sum_{bj64 <= row>>6} Rpart[b][bj64][row]
__global__ __launch_bounds__(256) void rowsum(
    const float* __restrict__ Rpart, float* __restrict__ Rinv) {
  const int t = blockIdx.x * 256 + threadIdx.x;  // 0..8191
  const int b = t >> 11, row = t & 2047;
  const int nb = (row >> 6) + 1;
  float s = 0.f;
  for (int bj = 0; bj < nb; ++bj) s += Rpart[(b * 32 + bj) * 2048 + row];
  Rinv[t] = 1.f / s;
}

// O = (P V) * Rinv ; grid 1024. Per-XCD balanced LPT: XCD c gets 8 blocks of
// EVERY bi, heavy-first; per (c,bi) 8 blocks share one (b, P-panel).
__global__ __launch_bounds__(256) void pv_kernel(
    const unsigned short* __restrict__ P, const unsigned short* __restrict__ Vt,
    const float* __restrict__ Rinv, float* __restrict__ out) {
  __shared__ __align__(16) unsigned short lA[4096], lB[2048];
  const int orig = blockIdx.x;
  const int c = orig & 7, i = orig >> 3;  // XCD, order within XCD (0..127)
  const int bi = 15 - (i >> 3);           // heavy-first
  const int rr = (i & 7) + c * 8;         // 0..63
  const int b = rr >> 4, bj = rr & 15;
  floatx4 acc[4][2] = {};
  gemm_loop32<2>(P + (long long)b * 2048 * 2048, Vt + (long long)b * 2048, 2048, 8192,
                 (bi + 1) * 4, bi, bj, lA, lB, acc);
  const int tid = threadIdx.x, wave = tid >> 6, lane = tid & 63;
  const int wr = wave >> 1, wc = wave & 1, frow = lane & 15, hi = lane >> 4;
  float* C = out + (long long)b * 2048 * 1024;
  const float* Ri = Rinv + b * 2048;
#pragma unroll
  for (int m = 0; m < 4; ++m)
#pragma unroll
    for (int j = 0; j < 4; ++j) {
      const int row = bi * 128 + wr * 64 + hi * 4 + m * 16 + j;
      const float riv = Ri[row];
      float* cp = C + (long long)row * 1024 + bj * 64 + wc * 32 + frow;
      cp[0] = acc[m][0][j] * riv;
      cp[16] = acc[m][1][j] * riv;
    }
}

// All fp32->bf16 converts, 16B stores (8 elems/thread/iter). Grid 2048 (R9).
__global__ __launch_bounds__(256) void cvtAll(
    const float* __restrict__ Xk, const float* __restrict__ Xv,
    const float* __restrict__ Xq, const float* __restrict__ Wq,
    const float* __restrict__ Wk, const float* __restrict__ Wv,
    unsigned short* __restrict__ Xb, unsigned short* __restrict__ WqB,
    unsigned short* __restrict__ WkB, unsigned short* __restrict__ WvT) {
  __shared__ unsigned short tile[64][65];
  const int bx = blockIdx.x, t = threadIdx.x;
  if (bx < 1536) {
    const int y = bx / 512, sub = bx - y * 512;
    const float* in = y == 0 ? Xv : (y == 1 ? Xq : Xk);
    unsigned short* o = Xb + (long long)y * XE;
    const int n8 = (int)(XE / 8), stride = 512 * 256;
    for (int i = sub * 256 + t; i < n8; i += stride) {
      float4 a = ((const float4*)in)[2 * i];
      float4 d = ((const float4*)in)[2 * i + 1];
      short8 v;
      v[0] = (short)f2b(a.x); v[1] = (short)f2b(a.y);
      v[2] = (short)f2b(a.z); v[3] = (short)f2b(a.w);
      v[4] = (short)f2b(d.x); v[5] = (short)f2b(d.y);
      v[6] = (short)f2b(d.z); v[7] = (short)f2b(d.w);
      ((short8*)o)[i] = v;
    }
  } else if (bx < 1792) {
    const int w2 = bx - 1536;
    const int y = w2 >> 7, sub = w2 & 127;
    const float* in = y == 0 ? Wq : Wk;
    unsigned short* o = y == 0 ? WqB : WkB;
    const int n8 = (int)(WE / 8), stride = 128 * 256;
    for (int i = sub * 256 + t; i < n8; i += stride) {
      float4 a = ((const float4*)in)[2 * i];
      float4 d = ((const float4*)in)[2 * i + 1];
      short8 v;
      v[0] = (short)f2b(a.x); v[1] = (short)f2b(a.y);
      v[2] = (short)f2b(a.z); v[3] = (short)f2b(a.w);
      v[4] = (short)f2b(d.x); v[5] = (short)f2b(d.y);
      v[6] = (short)f2b(d.z); v[7] = (short)f2b(d.w);
      ((short8*)o)[i] = v;
    }
  } else {
    const int v = bx - 1792;
    const int i0 = (v & 15) * 64, j0 = (v >> 4) * 64;
#pragma unroll
    for (int r = 0; r < 16; ++r) {
      int lin = r * 256 + t;
      int i = lin >> 6, j = lin & 63;
      tile[i][j] = f2b(Wv[(long long)(i0 + i) * 1024 + j0 + j]);
    }
    __syncthreads();
#pragma unroll
    for (int r = 0; r < 16; ++r) {
      int lin = r * 256 + t;
      int o = lin >> 6, i = lin & 63;
      WvT[(long long)(j0 + o) * 1024 + i0 + i] = tile[i][o];
    }
  }
}

extern "C" void kernel_launch(void* const* d_in, const int* in_sizes, int n_in,
                              void* d_out, int out_size, void* d_ws, size_t ws_size,
                              hipStream_t stream) {
  const float* Xk = (const float*)d_in[0];
  const float* Xv = (const float*)d_in[1];
  const float* Xq = (const float*)d_in[2];
  const float* Wk = (const float*)d_in[3];
  const float* Wv = (const float*)d_in[4];
  const float* Wq = (const float*)d_in[5];
  float* out = (float*)d_out;

  // ws (ushort elems): Xb[3XE: Xv|Xq|Xk] WqB[WE] WkB[WE] WvT[WE] Gt[WE]
  //                    Tb[XE] Vt[XE] Rpart[4*32*2048 f32] Rinv[8192 f32]
  // Pbuf (bf16 P, 2XE) aliases Xv|Xq ONLY (both dead after projTV8).
  unsigned short* ws = (unsigned short*)d_ws;
  unsigned short* Xb = ws;
  unsigned short* WqB = ws + 3 * XE;
  unsigned short* WkB = WqB + WE;
  unsigned short* WvT = WkB + WE;
  unsigned short* Gt = WvT + WE;
  unsigned short* Tb = Gt + WE;
  unsigned short* Vt = Tb + XE;
  float* Rpart = (float*)(Vt + XE);
  float* Rinv = Rpart + 4 * 32 * 2048;
  unsigned short* Pbuf = ws;  // alias over Xv|Xq

  cvtAll<<<2048, 256, 0, stream>>>(Xk, Xv, Xq, Wq, Wk, Wv, Xb, WqB, WkB, WvT);
  gt_kernel<<<dim3(8, 8), 256, 0, stream>>>(WkB, WqB, Gt);
  projTV8<<<256, 512, 131072, stream>>>(Xb, WvT, Gt, Tb, Vt);
  scores_exp<<<1088, 256, 0, stream>>>(Tb, Xb + 2 * XE, Pbuf, Rpart);
  rowsum<<<32, 256, 0, stream>>>(Rpart, Rinv);
  pv_kernel<<<1024, 256, 0, stream>>>(Pbuf, Vt, Rinv, out);
}

// Round 14
// 150.199 us; speedup vs baseline: 1.1540x; 1.1463x over previous
//
#include <hip/hip_runtime.h>

// AttentionHead: B=4, S=2048, D=1024, fp32 in/out, bf16 MFMA compute.
// G = Wq·Wk^T  =>  S = Xq·G·Xk^T (K-projection eliminated).
// Max-free softmax: P = exp(S/32) fused into scores epilogue + row-sum partials;
// PV scales by 1/rowsum.
// projTV + scores: 256x256 8-phase pipelined core. pv/gt: BK=64 single-buffer.

typedef __attribute__((ext_vector_type(8))) short short8;
typedef __attribute__((ext_vector_type(4))) float floatx4;

static constexpr long long XE = 8388608LL;  // 4*2048*1024
static constexpr long long WE = 1048576LL;  // 1024*1024

static __device__ __forceinline__ unsigned short f2b(float f) {
  unsigned u = __builtin_bit_cast(unsigned, f);
  u = (u + 0x7fffu + ((u >> 16) & 1u)) >> 16;
  return (unsigned short)u;
}

static __device__ __forceinline__ void gload16(const unsigned short* g, unsigned short* l) {
  __builtin_amdgcn_global_load_lds(
      (const __attribute__((address_space(1))) unsigned int*)g,
      (__attribute__((address_space(3))) unsigned int*)l, 16, 0, 0);
}

#define VMCNT(n) asm volatile("s_waitcnt vmcnt(" #n ")" ::: "memory")
#define LGKM0() asm volatile("s_waitcnt lgkmcnt(0)" ::: "memory")
#define BARRIER() do { asm volatile("" ::: "memory"); __builtin_amdgcn_s_barrier(); asm volatile("" ::: "memory"); } while (0)

// ============ 256x256, BK=64x2, 8-wave, 8-phase core macros ============
#define STAGE(base, matoff, h, slot, kt) do {                                  \
    const unsigned short* _s = (base) + (h) * 131072 + (kt) * 64;              \
    char* _d = sb + (slot) * 65536 + (matoff) + (h) * 16384 + dwave;           \
    gload16(_s, (unsigned short*)_d);                                          \
    gload16(_s + 65536, (unsigned short*)(_d + 8192));                         \
  } while (0)

#define READ_A(slot, mb) do {                                                  \
    const char* _p = sb + (slot) * 65536 + aoffb + (mb) * 2048;                \
    af[0][0] = *(const short8*)(_p + c0);        af[0][1] = *(const short8*)(_p + c1); \
    af[1][0] = *(const short8*)(_p + 2048 + c0); af[1][1] = *(const short8*)(_p + 2048 + c1); \
    af[2][0] = *(const short8*)(_p + 4096 + c0); af[2][1] = *(const short8*)(_p + 4096 + c1); \
    af[3][0] = *(const short8*)(_p + 6144 + c0); af[3][1] = *(const short8*)(_p + 6144 + c1); \
  } while (0)

#define READ_B(slot, nb, bfx) do {                                             \
    const char* _p = sb + (slot) * 65536 + boffb + (nb) * 2048;                \
    bfx[0][0] = *(const short8*)(_p + c0);        bfx[0][1] = *(const short8*)(_p + c1); \
    bfx[1][0] = *(const short8*)(_p + 2048 + c0); bfx[1][1] = *(const short8*)(_p + 2048 + c1); \
  } while (0)

#define MF16(MB, NB, bfx) do {                                                 \
    __builtin_amdgcn_s_setprio(1);                                             \
    _Pragma("unroll")                                                          \
    for (int _m = 0; _m < 4; ++_m) {                                           \
      _Pragma("unroll")                                                        \
      for (int _n = 0; _n < 2; ++_n) {                                         \
        acc[(MB) + _m][(NB) + _n] = __builtin_amdgcn_mfma_f32_16x16x32_bf16(   \
            af[_m][0], bfx[_n][0], acc[(MB) + _m][(NB) + _n], 0, 0, 0);        \
        acc[(MB) + _m][(NB) + _n] = __builtin_amdgcn_mfma_f32_16x16x32_bf16(   \
            af[_m][1], bfx[_n][1], acc[(MB) + _m][(NB) + _n], 0, 0, 0);        \
      } }                                                                      \
    __builtin_amdgcn_s_setprio(0);                                             \
  } while (0)

// The shared 8-phase K-loop body (K=1024). Declares af/bf0/bf1/acc; uses
// Ab/Bb/aoffb/boffb/c0/c1/dwave from enclosing scope.
#define KLOOP8()                                                               \
  STAGE(Ab, 0, 0, 0, 0);     STAGE(Ab, 0, 1, 0, 0);                            \
  STAGE(Bb, 32768, 0, 0, 0); STAGE(Bb, 32768, 1, 0, 0);                        \
  STAGE(Bb, 32768, 0, 1, 1); STAGE(Bb, 32768, 1, 1, 1);                        \
  VMCNT(4);                                                                    \
  BARRIER();                                                                   \
  for (int t = 0; t < 8; ++t) {                                                \
    const int kt1 = 2 * t + 1, kt2 = 2 * t + 2, kt3 = 2 * t + 3;               \
    const bool pf = t < 7;                                                     \
    READ_A(0, 0); READ_B(0, 0, bf0);                                           \
    STAGE(Ab, 0, 0, 1, kt1);                                                   \
    BARRIER(); LGKM0();                                                        \
    MF16(0, 0, bf0);                                                           \
    BARRIER();                                                                 \
    READ_B(0, 2, bf1);                                                         \
    STAGE(Ab, 0, 1, 1, kt1);                                                   \
    BARRIER(); LGKM0();                                                        \
    MF16(0, 2, bf1);                                                           \
    BARRIER();                                                                 \
    READ_A(0, 4);                                                              \
    if (pf) STAGE(Bb, 32768, 0, 0, kt2);                                       \
    BARRIER(); LGKM0();                                                        \
    MF16(4, 2, bf1);                                                           \
    BARRIER();                                                                 \
    if (pf) STAGE(Bb, 32768, 1, 0, kt2);                                       \
    BARRIER();                                                                 \
    MF16(4, 0, bf0);                                                           \
    if (pf) { VMCNT(4); } else { VMCNT(0); }                                   \
    BARRIER();                                                                 \
    READ_A(1, 0); READ_B(1, 0, bf0);                                           \
    if (pf) STAGE(Ab, 0, 0, 0, kt2);                                           \
    BARRIER(); LGKM0();                                                        \
    MF16(0, 0, bf0);                                                           \
    BARRIER();                                                                 \
    READ_B(1, 2, bf1);                                                         \
    if (pf) STAGE(Ab, 0, 1, 0, kt2);                                           \
    BARRIER(); LGKM0();                                                        \
    MF16(0, 2, bf1);                                                           \
    BARRIER();                                                                 \
    READ_A(1, 4);                                                              \
    if (pf) STAGE(Bb, 32768, 0, 1, kt3);                                       \
    BARRIER(); LGKM0();                                                        \
    MF16(4, 2, bf1);                                                           \
    BARRIER();                                                                 \
    if (pf) STAGE(Bb, 32768, 1, 1, kt3);                                       \
    BARRIER();                                                                 \
    MF16(4, 0, bf0);                                                           \
    if (pf) { VMCNT(4); } else { VMCNT(0); }                                   \
    BARRIER();                                                                 \
  }

__global__ __launch_bounds__(512, 2) void projTV8(
    const unsigned short* __restrict__ Xb, const unsigned short* __restrict__ WvT,
    const unsigned short* __restrict__ Gt, unsigned short* __restrict__ Tb,
    unsigned short* __restrict__ Vt) {
  extern __shared__ char sb[];
  const int orig = blockIdx.x;
  const int w = (orig & 7) * 32 + (orig >> 3);  // 256 = 8*32
  const unsigned short *Aop, *Bop;
  unsigned short* C;
  int ldc, bi, bj;
  if (w < 128) { Aop = Xb + XE; Bop = Gt; C = Tb; ldc = 1024; bi = w >> 2; bj = w & 3; }
  else { const int j = w - 128; Aop = WvT; Bop = Xb; C = Vt; ldc = 8192; bi = j & 3; bj = j >> 2; }

  const int tid = threadIdx.x, wave = tid >> 6, lane = tid & 63;
  const int wm = wave >> 2, wn = wave & 3, frow = lane & 15, hi = lane >> 4;
  const int r0 = tid >> 3, p0 = ((tid & 7) ^ (r0 & 7)) * 8;
  const int dwave = wave * 1024;
  const int sx = frow & 7;
  const int c0 = (hi ^ sx) * 16, c1 = ((4 + hi) ^ sx) * 16;
  const int aoffb = (wm * 128 + frow) * 128;
  const int boffb = 32768 + (wn * 64 + frow) * 128;
  const unsigned short* Ab = Aop + (long long)(bi * 256 + r0) * 1024 + p0;
  const unsigned short* Bb = Bop + (long long)(bj * 256 + r0) * 1024 + p0;

  short8 af[4][2], bf0[2][2], bf1[2][2];
  floatx4 acc[8][4] = {};

  KLOOP8();

  const long long crow0 = (long long)bi * 256 + wm * 128 + hi * 4;
  const int ccol = bj * 256 + wn * 64 + frow;
#pragma unroll
  for (int m = 0; m < 8; ++m)
#pragma unroll
    for (int j = 0; j < 4; ++j) {
      unsigned short* cp = C + (crow0 + m * 16 + j) * (long long)ldc + ccol;
#pragma unroll
      for (int n = 0; n < 4; ++n) cp[n * 16] = f2b(acc[m][n][j]);
    }
}

// scores on the 8-phase core: grid 144 (=8*18, XCD-swizzled), 256x256 tri
// tiles. S = T·Xk^T ; P = exp(S/32) bf16 (causal on diag tiles) ;
// row-sum partials -> Rpart[b][bj256][2048].
__global__ __launch_bounds__(512, 2) void scores_exp8(
    const unsigned short* __restrict__ Tb, const unsigned short* __restrict__ Xk,
    unsigned short* __restrict__ P, float* __restrict__ Rpart) {
  extern __shared__ char sb[];
  const int orig = blockIdx.x;
  const int w = (orig & 7) * 18 + (orig >> 3);  // 144 = 8*18
  const int b = w / 36;
  int t2 = w - b * 36;
  int bi = 0;
  while (t2 >= bi + 1) { t2 -= bi + 1; ++bi; }
  const int bj = t2;

  const unsigned short* Aop = Tb + (long long)b * 2048 * 1024;
  const unsigned short* Bop = Xk + (long long)b * 2048 * 1024;

  const int tid = threadIdx.x, wave = tid >> 6, lane = tid & 63;
  const int wm = wave >> 2, wn = wave & 3, frow = lane & 15, hi = lane >> 4;
  const int r0 = tid >> 3, p0 = ((tid & 7) ^ (r0 & 7)) * 8;
  const int dwave = wave * 1024;
  const int sx = frow & 7;
  const int c0 = (hi ^ sx) * 16, c1 = ((4 + hi) ^ sx) * 16;
  const int aoffb = (wm * 128 + frow) * 128;
  const int boffb = 32768 + (wn * 64 + frow) * 128;
  const unsigned short* Ab = Aop + (long long)(bi * 256 + r0) * 1024 + p0;
  const unsigned short* Bb = Bop + (long long)(bj * 256 + r0) * 1024 + p0;

  short8 af[4][2], bf0[2][2], bf1[2][2];
  floatx4 acc[8][4] = {};

  KLOOP8();

  // Epilogue: exp, causal mask (diag tiles), P write, row-sum partials.
  const bool diag = (bi == bj);
  unsigned short* C = P + (long long)b * 2048 * 2048;
  float rs[8][4];
#pragma unroll
  for (int m = 0; m < 8; ++m)
#pragma unroll
    for (int j = 0; j < 4; ++j) {
      const int row_loc = wm * 128 + hi * 4 + m * 16 + j;
      const int row_glob = bi * 256 + row_loc;
      unsigned short* cp = C + (long long)row_glob * 2048 + bj * 256 + wn * 64 + frow;
      float s = 0.f;
#pragma unroll
      for (int n = 0; n < 4; ++n) {
        const int col = bj * 256 + wn * 64 + n * 16 + frow;
        float e = __expf(acc[m][n][j] * 0.03125f);
        if (diag && col > row_glob) e = 0.f;
        cp[n * 16] = f2b(e);
        s += e;
      }
      s += __shfl_xor(s, 1);
      s += __shfl_xor(s, 2);
      s += __shfl_xor(s, 4);
      s += __shfl_xor(s, 8);
      rs[m][j] = s;
    }
  __syncthreads();
  float* red = (float*)sb;  // 256 rows x 4 wn = 4 KB
  if (frow == 0) {
#pragma unroll
    for (int m = 0; m < 8; ++m)
#pragma unroll
      for (int j = 0; j < 4; ++j)
        red[(wm * 128 + hi * 4 + m * 16 + j) * 4 + wn] = rs[m][j];
  }
  __syncthreads();
  if (tid < 256)
    Rpart[((long long)b * 8 + bj) * 2048 + bi * 256 + tid] =
        red[tid * 4] + red[tid * 4 + 1] + red[tid * 4 + 2] + red[tid * 4 + 3];
}

// ============ single-buffer BK=64 core (gt / pv) — R9-proven ============
template <int NF>
static __device__ __forceinline__ void gemm_loop(
    const unsigned short* __restrict__ A, const unsigned short* __restrict__ Bt,
    int lda, int ldb, int nk, int bi, int bj,
    unsigned short* lA, unsigned short* lB, floatx4 acc[4][NF]) {
  const int t = threadIdx.x, wave = t >> 6, lane = t & 63;
  const int wr = wave >> 1, wc = wave & 1;
  const int sr = lane >> 3;
  const int sc = ((lane & 7) ^ sr) * 8;
  const unsigned short* gA = A + (long long)(bi * 128 + wave * 32 + sr) * lda + sc;
  const unsigned short* gB = Bt + (long long)(bj * (NF * 32) + wave * (NF * 8) + sr) * ldb + sc;
  unsigned short* lAw = lA + wave * 2048;
  unsigned short* lBw = lB + wave * (NF * 512);
  const int frow = lane & 15, hi = lane >> 4;

  for (int ks = 0; ks < nk; ++ks) {
    const long long k0 = (long long)ks * 64;
    __syncthreads();
#pragma unroll
    for (int g = 0; g < 4; ++g)
      gload16(gA + (long long)g * 8 * lda + k0, lAw + g * 512);
#pragma unroll
    for (int g = 0; g < NF; ++g)
      gload16(gB + (long long)g * 8 * ldb + k0, lBw + g * 512);
    __syncthreads();
#pragma unroll
    for (int kk = 0; kk < 2; ++kk) {
      const int ch = (kk * 4 + hi) ^ (frow & 7);
      short8 af[4], bf[NF];
#pragma unroll
      for (int m = 0; m < 4; ++m)
        af[m] = *(const short8*)&lA[(wr * 64 + m * 16 + frow) * 64 + ch * 8];
#pragma unroll
      for (int n = 0; n < NF; ++n)
        bf[n] = *(const short8*)&lB[(wc * (NF * 16) + n * 16 + frow) * 64 + ch * 8];
#pragma unroll
      for (int m = 0; m < 4; ++m)
#pragma unroll
        for (int n = 0; n < NF; ++n)
          acc[m][n] = __builtin_amdgcn_mfma_f32_16x16x32_bf16(af[m], bf[n], acc[m][n], 0, 0, 0);
    }
  }
}

// Gt[j][i] = sum_d Wk[j][d]*Wq[i][d], grid (8,8)
__global__ __launch_bounds__(256) void gt_kernel(
    const unsigned short* __restrict__ WkB, const unsigned short* __restrict__ WqB,
    unsigned short* __restrict__ Gt) {
  __shared__ __align__(16) unsigned short lA[8192], lB[8192];
  floatx4 acc[4][4] = {};
  gemm_loop<4>(WkB, WqB, 1024, 1024, 16, blockIdx.x, blockIdx.y, lA, lB, acc);
  const int tid = threadIdx.x, wave = tid >> 6, lane = tid & 63;
  const int wr = wave >> 1, wc = wave & 1, frow = lane & 15, hi = lane >> 4;
  const long long crow0 = (long long)blockIdx.x * 128 + wr * 64 + hi * 4;
  const int ccol = blockIdx.y * 128 + wc * 64 + frow;
#pragma unroll
  for (int m = 0; m < 4; ++m)
#pragma unroll
    for (int j = 0; j < 4; ++j) {
      unsigned short* cp = Gt + (crow0 + m * 16 + j) * 1024 + ccol;
#pragma unroll
      for (int n = 0; n < 4; ++n) cp[n * 16] = f2b(acc[m][n][j]);
    }
}

// Rinv[b][row] = 1 / sum_{bj256 <= row>>8} Rpart[b][bj256][row]
__global__ __launch_bounds__(256) void rowsum(
    const float* __restrict__ Rpart, float* __restrict__ Rinv) {
  const int t = blockIdx.x * 256 + threadIdx.x;  // 0..8191
  const int b = t >> 11, row = t & 2047;
  const int nb = (row >> 8) + 1;
  float s = 0.f;
  for (int bj = 0; bj < nb; ++bj) s += Rpart[(b * 8 + bj) * 2048 + row];
  Rinv[t] = 1.f / s;
}

// O = (P V) * Rinv ; grid 1024 (R9-proven). Per-XCD balanced LPT.
__global__ __launch_bounds__(256) void pv_kernel(
    const unsigned short* __restrict__ P, const unsigned short* __restrict__ Vt,
    const float* __restrict__ Rinv, float* __restrict__ out) {
  __shared__ __align__(16) unsigned short lA[8192], lB[4096];
  const int orig = blockIdx.x;
  const int c = orig & 7, i = orig >> 3;  // XCD, order within XCD (0..127)
  const int bi = 15 - (i >> 3);           // heavy-first
  const int rr = (i & 7) + c * 8;         // 0..63
  const int b = rr >> 4, bj = rr & 15;
  floatx4 acc[4][2] = {};
  gemm_loop<2>(P + (long long)b * 2048 * 2048, Vt + (long long)b * 2048, 2048, 8192,
               (bi + 1) * 2, bi, bj, lA, lB, acc);
  const int tid = threadIdx.x, wave = tid >> 6, lane = tid & 63;
  const int wr = wave >> 1, wc = wave & 1, frow = lane & 15, hi = lane >> 4;
  float* C = out + (long long)b * 2048 * 1024;
  const float* Ri = Rinv + b * 2048;
#pragma unroll
  for (int m = 0; m < 4; ++m)
#pragma unroll
    for (int j = 0; j < 4; ++j) {
      const int row = bi * 128 + wr * 64 + hi * 4 + m * 16 + j;
      const float riv = Ri[row];
      float* cp = C + (long long)row * 1024 + bj * 64 + wc * 32 + frow;
      cp[0] = acc[m][0][j] * riv;
      cp[16] = acc[m][1][j] * riv;
    }
}

// All fp32->bf16 converts, 16B stores (8 elems/thread/iter). Grid 2048 (R9).
__global__ __launch_bounds__(256) void cvtAll(
    const float* __restrict__ Xk, const float* __restrict__ Xv,
    const float* __restrict__ Xq, const float* __restrict__ Wq,
    const float* __restrict__ Wk, const float* __restrict__ Wv,
    unsigned short* __restrict__ Xb, unsigned short* __restrict__ WqB,
    unsigned short* __restrict__ WkB, unsigned short* __restrict__ WvT) {
  __shared__ unsigned short tile[64][65];
  const int bx = blockIdx.x, t = threadIdx.x;
  if (bx < 1536) {
    const int y = bx / 512, sub = bx - y * 512;
    const float* in = y == 0 ? Xv : (y == 1 ? Xq : Xk);
    unsigned short* o = Xb + (long long)y * XE;
    const int n8 = (int)(XE / 8), stride = 512 * 256;
    for (int i = sub * 256 + t; i < n8; i += stride) {
      float4 a = ((const float4*)in)[2 * i];
      float4 d = ((const float4*)in)[2 * i + 1];
      short8 v;
      v[0] = (short)f2b(a.x); v[1] = (short)f2b(a.y);
      v[2] = (short)f2b(a.z); v[3] = (short)f2b(a.w);
      v[4] = (short)f2b(d.x); v[5] = (short)f2b(d.y);
      v[6] = (short)f2b(d.z); v[7] = (short)f2b(d.w);
      ((short8*)o)[i] = v;
    }
  } else if (bx < 1792) {
    const int w2 = bx - 1536;
    const int y = w2 >> 7, sub = w2 & 127;
    const float* in = y == 0 ? Wq : Wk;
    unsigned short* o = y == 0 ? WqB : WkB;
    const int n8 = (int)(WE / 8), stride = 128 * 256;
    for (int i = sub * 256 + t; i < n8; i += stride) {
      float4 a = ((const float4*)in)[2 * i];
      float4 d = ((const float4*)in)[2 * i + 1];
      short8 v;
      v[0] = (short)f2b(a.x); v[1] = (short)f2b(a.y);
      v[2] = (short)f2b(a.z); v[3] = (short)f2b(a.w);
      v[4] = (short)f2b(d.x); v[5] = (short)f2b(d.y);
      v[6] = (short)f2b(d.z); v[7] = (short)f2b(d.w);
      ((short8*)o)[i] = v;
    }
  } else {
    const int v = bx - 1792;
    const int i0 = (v & 15) * 64, j0 = (v >> 4) * 64;
#pragma unroll
    for (int r = 0; r < 16; ++r) {
      int lin = r * 256 + t;
      int i = lin >> 6, j = lin & 63;
      tile[i][j] = f2b(Wv[(long long)(i0 + i) * 1024 + j0 + j]);
    }
    __syncthreads();
#pragma unroll
    for (int r = 0; r < 16; ++r) {
      int lin = r * 256 + t;
      int o = lin >> 6, i = lin & 63;
      WvT[(long long)(j0 + o) * 1024 + i0 + i] = tile[i][o];
    }
  }
}

extern "C" void kernel_launch(void* const* d_in, const int* in_sizes, int n_in,
                              void* d_out, int out_size, void* d_ws, size_t ws_size,
                              hipStream_t stream) {
  const float* Xk = (const float*)d_in[0];
  const float* Xv = (const float*)d_in[1];
  const float* Xq = (const float*)d_in[2];
  const float* Wk = (const float*)d_in[3];
  const float* Wv = (const float*)d_in[4];
  const float* Wq = (const float*)d_in[5];
  float* out = (float*)d_out;

  // ws (ushort elems): Xb[3XE: Xv|Xq|Xk] WqB[WE] WkB[WE] WvT[WE] Gt[WE]
  //                    Tb[XE] Vt[XE] Rpart[4*8*2048 f32] Rinv[8192 f32]
  // Pbuf (bf16 P, 2XE) aliases Xv|Xq ONLY (both dead after projTV8).
  unsigned short* ws = (unsigned short*)d_ws;
  unsigned short* Xb = ws;
  unsigned short* WqB = ws + 3 * XE;
  unsigned short* WkB = WqB + WE;
  unsigned short* WvT = WkB + WE;
  unsigned short* Gt = WvT + WE;
  unsigned short* Tb = Gt + WE;
  unsigned short* Vt = Tb + XE;
  float* Rpart = (float*)(Vt + XE);
  float* Rinv = Rpart + 4 * 8 * 2048;
  unsigned short* Pbuf = ws;  // alias over Xv|Xq

  cvtAll<<<2048, 256, 0, stream>>>(Xk, Xv, Xq, Wq, Wk, Wv, Xb, WqB, WkB, WvT);
  gt_kernel<<<dim3(8, 8), 256, 0, stream>>>(WkB, WqB, Gt);
  projTV8<<<256, 512, 131072, stream>>>(Xb, WvT, Gt, Tb, Vt);
  scores_exp8<<<144, 512, 131072, stream>>>(Tb, Xb + 2 * XE, Pbuf, Rpart);
  rowsum<<<32, 256, 0, stream>>>(Rpart, Rinv);
  pv_kernel<<<1024, 256, 0, stream>>>(Pbuf, Vt, Rinv, out);
}